// Round 3
// baseline (83.122 us; speedup 1.0000x reference)
//
#include <hip/hip_runtime.h>
#include <hip/hip_bf16.h>
#include <math.h>

constexpr int HW = 4096;   // 64*64

using bf8   = __attribute__((ext_vector_type(8))) short;   // 8 bf16 = 4 VGPR
using f32x4 = __attribute__((ext_vector_type(4))) float;

__device__ inline float blo(unsigned u) { return __uint_as_float(u << 16); }
__device__ inline float bhi(unsigned u) { return __uint_as_float(u & 0xffff0000u); }

// ---------------------------------------------------------------------------
// prep: xT[8192][128] bf16 (pixel-major transpose of x) + weight bf16 copies
//   Wb[768][128]  = [Wk; Wq; Wv] rows, bf16
//   Wob[128][256] = Wo, bf16
// grid: 144 blocks x 256 thr
// ---------------------------------------------------------------------------
__global__ __launch_bounds__(256) void prep(
    const float* __restrict__ x,
    const float* __restrict__ Wk, const float* __restrict__ Wq,
    const float* __restrict__ Wv, const float* __restrict__ Wo,
    __hip_bfloat16* __restrict__ xT, __hip_bfloat16* __restrict__ Wb,
    __hip_bfloat16* __restrict__ Wob)
{
    int blk = blockIdx.x;
    int t   = threadIdx.x;
    if (blk < 128) {
        int px0 = blk * 64;          // global pixel row (b folded: 0..8191)
        int b   = px0 >> 12;
        int hw0 = px0 & 4095;
        int px  = t & 63;
        int cg0 = t >> 6;            // 0..3
        const float* xb = x + (size_t)b * 128 * HW + hw0 + px;
        #pragma unroll
        for (int it = 0; it < 4; ++it) {
            int c0 = (it * 4 + cg0) * 8;
            union { __hip_bfloat16 h[8]; uint4 u; } pk;
            #pragma unroll
            for (int j = 0; j < 8; ++j)
                pk.h[j] = __float2bfloat16(xb[(size_t)(c0 + j) * HW]);
            *(uint4*)&xT[(size_t)(px0 + px) * 128 + c0] = pk.u;
        }
    } else {
        // 131072 total weight elems: 98304 (Wb) + 32768 (Wob)
        for (int i = (blk - 128) * 256 + t; i < 131072; i += 4096) {
            if (i < 98304) {
                float v;
                if (i < 32768)      v = Wk[i];
                else if (i < 65536) v = Wq[i - 32768];
                else                v = Wv[i - 65536];
                Wb[i] = __float2bfloat16(v);
            } else {
                Wob[i - 98304] = __float2bfloat16(Wo[i - 98304]);
            }
        }
    }
}

// ---------------------------------------------------------------------------
// qkv MFMA GEMM: qkv[px][oc] = sum_c xT[px][c] * Wb[oc][c] + bias
// A = xT tile (16px x 32c), B = Wb rows (32c x 16oc), D[px][oc].
// Block: 4 waves, tile 64px x 64oc. grid (128, 12).
// Output: qkv fp32 pixel-major [8192][768]  (K 0-255 | Q 256-511 | V 512-767)
// ---------------------------------------------------------------------------
__global__ __launch_bounds__(256) void qkv_mfma(
    const __hip_bfloat16* __restrict__ xT, const __hip_bfloat16* __restrict__ Wb,
    const float* __restrict__ bk, const float* __restrict__ bq,
    const float* __restrict__ bv, float* __restrict__ qkv)
{
    int t = threadIdx.x;
    int w = t >> 6, lane = t & 63;
    int m  = lane & 15;      // A-row / B-col / D-col index
    int kq = lane >> 4;      // k-quarter
    int px0 = blockIdx.x * 64 + w * 16;
    int oc0 = blockIdx.y * 64;
    const float* bias = blockIdx.y < 4 ? bk : blockIdx.y < 8 ? bq : bv;
    int ocl = (blockIdx.y & 3) * 64;

    const short* xr = (const short*)xT + (size_t)(px0 + m) * 128;
    bf8 aF[4];
    #pragma unroll
    for (int ks = 0; ks < 4; ++ks)
        aF[ks] = *(const bf8*)(xr + ks * 32 + kq * 8);

    f32x4 acc[4] = { {0.f,0.f,0.f,0.f}, {0.f,0.f,0.f,0.f},
                     {0.f,0.f,0.f,0.f}, {0.f,0.f,0.f,0.f} };
    const short* wb = (const short*)Wb + (size_t)oc0 * 128;
    #pragma unroll
    for (int ks = 0; ks < 4; ++ks) {
        #pragma unroll
        for (int of = 0; of < 4; ++of) {
            bf8 bF = *(const bf8*)(wb + (size_t)(of * 16 + m) * 128 + ks * 32 + kq * 8);
            acc[of] = __builtin_amdgcn_mfma_f32_16x16x32_bf16(aF[ks], bF, acc[of], 0, 0, 0);
        }
    }

    #pragma unroll
    for (int of = 0; of < 4; ++of) {
        float bval = bias[ocl + of * 16 + m];
        float* op = qkv + (size_t)(px0 + kq * 4) * 768 + oc0 + of * 16 + m;
        #pragma unroll
        for (int r = 0; r < 4; ++r)
            op[(size_t)r * 768] = acc[of][r] + bval;
    }
}

// ---------------------------------------------------------------------------
// Windowed attention. One block = (b, head, 8x8 tile), 256 thr = 64px x 4 dg.
// K/V halos staged as bf16 in LDS (14x14x32), logits/PV unpack via shift/mask.
// Output abT bf16 pixel-major [8192][256].
// ---------------------------------------------------------------------------
__global__ __launch_bounds__(256) void attn_win(
    const float* __restrict__ qkv, __hip_bfloat16* __restrict__ ab)
{
    __shared__ __align__(16) unsigned short S[196 * 32];   // [y*14+x][32ch] bf16

    int id   = blockIdx.x;
    int b    = id >> 9;
    int h    = (id >> 6) & 7;
    int tile = id & 63;
    int ty0  = (tile >> 3) * 8;
    int tx0  = (tile & 7) * 8;

    int t   = threadIdx.x;
    int pix = t >> 2, dg = t & 3;
    int py  = pix >> 3, px = pix & 7;
    int gy  = ty0 + py, gx = tx0 + px;

    size_t rowb = (size_t)b * 4096;
    int koff = h * 32, qoff = 256 + h * 32, voff = 512 + h * 32;

    // ---- stage K halo: 196 px x 4 chunks (8 ch each) ----
    for (int e = t; e < 784; e += 256) {
        int hp = e >> 2, c8 = e & 3;
        int y  = hp / 14, xc = hp - y * 14;
        int yy = ty0 - 3 + y, xx = tx0 - 3 + xc;
        union { __hip_bfloat16 h8[8]; uint4 u; } pk;
        pk.u = make_uint4(0u, 0u, 0u, 0u);
        if (yy >= 0 && yy < 64 && xx >= 0 && xx < 64) {
            const float* p = qkv + (rowb + yy * 64 + xx) * 768 + koff + c8 * 8;
            float4 a0 = *(const float4*)p;
            float4 a1 = *(const float4*)(p + 4);
            pk.h8[0] = __float2bfloat16(a0.x); pk.h8[1] = __float2bfloat16(a0.y);
            pk.h8[2] = __float2bfloat16(a0.z); pk.h8[3] = __float2bfloat16(a0.w);
            pk.h8[4] = __float2bfloat16(a1.x); pk.h8[5] = __float2bfloat16(a1.y);
            pk.h8[6] = __float2bfloat16(a1.z); pk.h8[7] = __float2bfloat16(a1.w);
        }
        *(uint4*)&S[(y * 14 + xc) * 32 + c8 * 8] = pk.u;
    }

    // ---- q (8 fp32 channels of this thread's d-group) ----
    float q[8];
    {
        const float* qp = qkv + (rowb + gy * 64 + gx) * 768 + qoff + dg * 8;
        float4 q0 = *(const float4*)qp;
        float4 q1 = *(const float4*)(qp + 4);
        q[0] = q0.x; q[1] = q0.y; q[2] = q0.z; q[3] = q0.w;
        q[4] = q1.x; q[5] = q1.y; q[6] = q1.z; q[7] = q1.w;
    }
    __syncthreads();

    // ---- partial logits ----
    float lg[49];
    #pragma unroll
    for (int dy = 0; dy < 7; ++dy) {
        #pragma unroll
        for (int dx = 0; dx < 7; ++dx) {
            uint4 kv = *(const uint4*)&S[((py + dy) * 14 + px + dx) * 32 + dg * 8];
            float a;
            a = q[0] * blo(kv.x);
            a = fmaf(q[1], bhi(kv.x), a);
            a = fmaf(q[2], blo(kv.y), a);
            a = fmaf(q[3], bhi(kv.y), a);
            a = fmaf(q[4], blo(kv.z), a);
            a = fmaf(q[5], bhi(kv.z), a);
            a = fmaf(q[6], blo(kv.w), a);
            a = fmaf(q[7], bhi(kv.w), a);
            lg[dy * 7 + dx] = a;
        }
    }

    // ---- quad reduce across the 4 d-groups ----
    #pragma unroll
    for (int a = 0; a < 49; ++a) {
        lg[a] += __shfl_xor(lg[a], 1);
        lg[a] += __shfl_xor(lg[a], 2);
    }

    // ---- softmax over 49 ----
    constexpr float scale = 0.17677669529663687f;  // 1/sqrt(32)
    float mx = lg[0];
    #pragma unroll
    for (int a = 1; a < 49; ++a) mx = fmaxf(mx, lg[a]);
    float s = 0.f;
    #pragma unroll
    for (int a = 0; a < 49; ++a) {
        lg[a] = __expf((lg[a] - mx) * scale);
        s += lg[a];
    }
    float inv = 1.f / s;

    __syncthreads();  // all K reads done

    // ---- stage V halo (reuse S) ----
    for (int e = t; e < 784; e += 256) {
        int hp = e >> 2, c8 = e & 3;
        int y  = hp / 14, xc = hp - y * 14;
        int yy = ty0 - 3 + y, xx = tx0 - 3 + xc;
        union { __hip_bfloat16 h8[8]; uint4 u; } pk;
        pk.u = make_uint4(0u, 0u, 0u, 0u);
        if (yy >= 0 && yy < 64 && xx >= 0 && xx < 64) {
            const float* p = qkv + (rowb + yy * 64 + xx) * 768 + voff + c8 * 8;
            float4 a0 = *(const float4*)p;
            float4 a1 = *(const float4*)(p + 4);
            pk.h8[0] = __float2bfloat16(a0.x); pk.h8[1] = __float2bfloat16(a0.y);
            pk.h8[2] = __float2bfloat16(a0.z); pk.h8[3] = __float2bfloat16(a0.w);
            pk.h8[4] = __float2bfloat16(a1.x); pk.h8[5] = __float2bfloat16(a1.y);
            pk.h8[6] = __float2bfloat16(a1.z); pk.h8[7] = __float2bfloat16(a1.w);
        }
        *(uint4*)&S[(y * 14 + xc) * 32 + c8 * 8] = pk.u;
    }
    __syncthreads();

    // ---- weighted sum ----
    float o[8] = {};
    #pragma unroll
    for (int dy = 0; dy < 7; ++dy) {
        #pragma unroll
        for (int dx = 0; dx < 7; ++dx) {
            float wgt = lg[dy * 7 + dx];
            uint4 vv = *(const uint4*)&S[((py + dy) * 14 + px + dx) * 32 + dg * 8];
            o[0] = fmaf(wgt, blo(vv.x), o[0]);
            o[1] = fmaf(wgt, bhi(vv.x), o[1]);
            o[2] = fmaf(wgt, blo(vv.y), o[2]);
            o[3] = fmaf(wgt, bhi(vv.y), o[3]);
            o[4] = fmaf(wgt, blo(vv.z), o[4]);
            o[5] = fmaf(wgt, bhi(vv.z), o[5]);
            o[6] = fmaf(wgt, blo(vv.w), o[6]);
            o[7] = fmaf(wgt, bhi(vv.w), o[7]);
        }
    }

    // ---- store pixel-major bf16: abT[px][256] ----
    union { __hip_bfloat16 h8[8]; uint4 u; } pk;
    #pragma unroll
    for (int j = 0; j < 8; ++j) pk.h8[j] = __float2bfloat16(o[j] * inv);
    *(uint4*)&ab[(rowb + gy * 64 + gx) * 256 + h * 32 + dg * 8] = pk.u;
}

// ---------------------------------------------------------------------------
// Output projection MFMA: out[b][oc][hw] = sum_c abT[px][c] * Wob[oc][c] + bo
// Block: 4 waves, tile 32px x 64oc (wave = 16px x 32oc). grid (256, 2).
// D[px][oc] frags -> LDS transpose -> coalesced channel-major store.
// ---------------------------------------------------------------------------
__global__ __launch_bounds__(256) void proj_mfma(
    const __hip_bfloat16* __restrict__ aT, const __hip_bfloat16* __restrict__ Wob,
    const float* __restrict__ bo, float* __restrict__ out)
{
    __shared__ float OutT[32][68];

    int t = threadIdx.x;
    int w = t >> 6, lane = t & 63;
    int m  = lane & 15;
    int kq = lane >> 4;
    int pw = w & 1, ow = w >> 1;
    int px0 = blockIdx.x * 32 + pw * 16;
    int ocb = blockIdx.y * 64 + ow * 32;

    const short* ar = (const short*)aT + (size_t)(px0 + m) * 256;
    f32x4 acc[2] = { {0.f,0.f,0.f,0.f}, {0.f,0.f,0.f,0.f} };
    #pragma unroll
    for (int ks = 0; ks < 8; ++ks) {
        bf8 aF = *(const bf8*)(ar + ks * 32 + kq * 8);
        #pragma unroll
        for (int of = 0; of < 2; ++of) {
            bf8 bF = *(const bf8*)((const short*)Wob +
                     (size_t)(ocb + of * 16 + m) * 256 + ks * 32 + kq * 8);
            acc[of] = __builtin_amdgcn_mfma_f32_16x16x32_bf16(aF, bF, acc[of], 0, 0, 0);
        }
    }

    #pragma unroll
    for (int of = 0; of < 2; ++of) {
        float bval = bo[ocb + of * 16 + m];
        #pragma unroll
        for (int r = 0; r < 4; ++r)
            OutT[pw * 16 + kq * 4 + r][ow * 32 + of * 16 + m] = acc[of][r] + bval;
    }
    __syncthreads();

    int pxl = t & 31, ocg = t >> 5;
    int gpx = blockIdx.x * 32 + pxl;
    int b   = gpx >> 12, hw = gpx & 4095;
    #pragma unroll
    for (int i = 0; i < 8; ++i) {
        int oc = blockIdx.y * 64 + ocg * 8 + i;
        out[((size_t)b * 128 + oc) * HW + hw] = OutT[pxl][ocg * 8 + i];
    }
}

// ---------------------------------------------------------------------------
extern "C" void kernel_launch(void* const* d_in, const int* in_sizes, int n_in,
                              void* d_out, int out_size, void* d_ws, size_t ws_size,
                              hipStream_t stream) {
    const float* x  = (const float*)d_in[0];
    const float* Wk = (const float*)d_in[1];
    const float* bk = (const float*)d_in[2];
    const float* Wq = (const float*)d_in[3];
    const float* bq = (const float*)d_in[4];
    const float* Wv = (const float*)d_in[5];
    const float* bv = (const float*)d_in[6];
    const float* Wo = (const float*)d_in[7];
    const float* bo = (const float*)d_in[8];
    float* out = (float*)d_out;

    char* wsb = (char*)d_ws;
    __hip_bfloat16* xT  = (__hip_bfloat16*)wsb;                        // 2 MB
    __hip_bfloat16* Wb  = (__hip_bfloat16*)(wsb + (2u << 20));         // 192 KB
    __hip_bfloat16* Wob = (__hip_bfloat16*)(wsb + (2u << 20) + 262144);// 64 KB
    float*          qkv = (float*)(wsb + (3u << 20));                  // 24 MB
    __hip_bfloat16* abT = (__hip_bfloat16*)(wsb + (3u << 20) + 25165824); // 4 MB

    prep<<<dim3(144), 256, 0, stream>>>(x, Wk, Wq, Wv, Wo, xT, Wb, Wob);
    qkv_mfma<<<dim3(128, 12), 256, 0, stream>>>(xT, Wb, bk, bq, bv, qkv);
    attn_win<<<dim3(1024), 256, 0, stream>>>(qkv, abT);
    proj_mfma<<<dim3(256, 2), 256, 0, stream>>>(abT, Wob, bo, out);
}